// Round 1
// 130.548 us; speedup vs baseline: 1.1574x; 1.1574x over previous
//
#include <hip/hip_runtime.h>
#include <hip/hip_bf16.h>

typedef unsigned short u16;
typedef __bf16 bf16x8 __attribute__((ext_vector_type(8)));
typedef float f32x4 __attribute__((ext_vector_type(4)));
typedef float f32x16 __attribute__((ext_vector_type(16)));
typedef unsigned u32x2 __attribute__((ext_vector_type(2)));
typedef unsigned u32x4 __attribute__((ext_vector_type(4)));

#define HIDDEN 1024
#define NH 16
#define HD 64
#define BATCH 2
#define SEQ 2048
#define MTOT (BATCH*SEQ)   // 4096
#define CEXP 0.18033688f   // 0.125 * log2(e), folded into Q at projection time

#if __has_builtin(__builtin_amdgcn_exp2f)
#define EXP2(x) __builtin_amdgcn_exp2f(x)
#else
#define EXP2(x) __builtin_exp2f(x)
#endif

__device__ __forceinline__ u16 f2bf(float f) {
  union { float f; unsigned u; } v; v.f = f;
  unsigned u = v.u;
  return (u16)((u + 0x7fffu + ((u >> 16) & 1u)) >> 16);   // RNE
}

__device__ __forceinline__ unsigned pack2bf(float a, float b) {
  __hip_bfloat162 h = __float22bfloat162_rn(make_float2(a, b));
  unsigned u; __builtin_memcpy(&u, &h, 4); return u;
}

__device__ __forceinline__ void gload16(const u16* g, u16* l) {
  __builtin_amdgcn_global_load_lds((const __attribute__((address_space(1))) unsigned int*)g,
                                   (__attribute__((address_space(3))) unsigned int*)l, 16, 0, 0);
}

// ---------------- prep: x fp32 -> bf16 ----------------
__global__ __launch_bounds__(256) void convert_x_kernel(const float* __restrict__ x,
                                                        u16* __restrict__ xb) {
  size_t i = ((size_t)blockIdx.x * 256 + threadIdx.x) * 4;
  float4 v = *(const float4*)(x + i);
  uint2 p;
  p.x = pack2bf(v.x, v.y);
  p.y = pack2bf(v.z, v.w);
  *(uint2*)(xb + i) = p;
}

// ---------------- prep: W (k,n) fp32 -> Wt (n,k) bf16 ----------------
__global__ __launch_bounds__(256) void transpose_w_kernel(const float* __restrict__ w0, const float* __restrict__ w1,
                                                          const float* __restrict__ w2, const float* __restrict__ w3,
                                                          u16* __restrict__ dqkv, u16* __restrict__ dwo) {
  __shared__ float t[32][33];
  int z = blockIdx.z;
  const float* src = (z==0) ? w0 : (z==1) ? w1 : (z==2) ? w2 : w3;
  u16* dst = (z < 3) ? (dqkv + (size_t)z * HIDDEN * HIDDEN) : dwo;
  int kb = blockIdx.x * 32, nb = blockIdx.y * 32;
  int tx = threadIdx.x & 31, ty = threadIdx.x >> 5;
  for (int r = ty; r < 32; r += 8) t[r][tx] = src[(size_t)(kb + r) * HIDDEN + nb + tx];
  __syncthreads();
  for (int r = ty; r < 32; r += 8) dst[(size_t)(nb + r) * HIDDEN + kb + tx] = f2bf(t[tx][r]);
}

// ---------------- prep: V (t,d) -> Vt (d,t) per head ----------------
__global__ __launch_bounds__(256) void transpose_v_kernel(const u16* __restrict__ qkv,
                                                          u16* __restrict__ vt) {
  __shared__ u16 t[32][33];
  int bh = blockIdx.z; int b = bh >> 4, h = bh & 15;
  int t0 = blockIdx.x * 32, d0 = blockIdx.y * 32;
  int tx = threadIdx.x & 31, ty = threadIdx.x >> 5;
  for (int r = ty; r < 32; r += 8)
    t[r][tx] = qkv[(size_t)(b*SEQ + t0 + r) * (3*HIDDEN) + 2*HIDDEN + h*HD + d0 + tx];
  __syncthreads();
  for (int r = ty; r < 32; r += 8)
    vt[(size_t)(bh*HD + d0 + r) * SEQ + t0 + tx] = t[tx][r];
}

// ---------------- bf16 GEMM: C[m,n] = sum_k A[m,k]*Bt[n,k] + bias ----------------
// MT x 128 tile (MT=128 or 64), BK=32, global_load_lds width-16 staging.
// MODE 0: fp32 out = acc + b0[n]                       (output projection)
// MODE 1: bf16 out, 3 segments: Q (scaled by CEXP), K, V -> qkvb
template<int MODE, int MT>
__global__ __launch_bounds__(256) void gemm_bt(const u16* __restrict__ A, const u16* __restrict__ Bt,
                                               const float* __restrict__ b0, const float* __restrict__ b1,
                                               const float* __restrict__ b2,
                                               u16* __restrict__ Cq, float* __restrict__ Cf,
                                               int M, int N, int K) {
  constexpr int MF = MT / 32;           // m-frags per wave: 4 (MT=128) or 2 (MT=64)
  __shared__ u16 As[MT*32];
  __shared__ u16 Bs[128*32];
  const int tid = threadIdx.x, lane = tid & 63, wv = tid >> 6;
  const int m0 = blockIdx.x * MT, n0 = blockIdx.y * 128;
  const int wm = (wv >> 1) * (MT/2), wn = (wv & 1) * 64;
  const int col = lane & 15, quad = lane >> 4;
  const int lr = lane >> 2, lk = (lane & 3) * 8;
  f32x4 acc[MF][4] = {};
  for (int k0 = 0; k0 < K; k0 += 32) {
    if constexpr (MT == 128) {
      gload16(&A[(size_t)(m0 + wv*32      + lr)*K + k0 + lk], &As[wv*1024]);
      gload16(&A[(size_t)(m0 + wv*32 + 16 + lr)*K + k0 + lk], &As[wv*1024 + 512]);
    } else {
      gload16(&A[(size_t)(m0 + wv*16      + lr)*K + k0 + lk], &As[wv*512]);
    }
    gload16(&Bt[(size_t)(n0 + wv*32      + lr)*K + k0 + lk], &Bs[wv*1024]);
    gload16(&Bt[(size_t)(n0 + wv*32 + 16 + lr)*K + k0 + lk], &Bs[wv*1024 + 512]);
    __syncthreads();
    bf16x8 af[MF], bfr[4];
    #pragma unroll
    for (int i = 0; i < MF; i++) af[i]  = *(const bf16x8*)&As[(wm + i*16 + col)*32 + quad*8];
    #pragma unroll
    for (int i = 0; i < 4; i++)  bfr[i] = *(const bf16x8*)&Bs[(wn + i*16 + col)*32 + quad*8];
    #pragma unroll
    for (int mi = 0; mi < MF; mi++)
      #pragma unroll
      for (int ni = 0; ni < 4; ni++)
        acc[mi][ni] = __builtin_amdgcn_mfma_f32_16x16x32_bf16(af[mi], bfr[ni], acc[mi][ni], 0, 0, 0);
    __syncthreads();
  }
  if constexpr (MODE == 0) {
    #pragma unroll
    for (int mi = 0; mi < MF; mi++)
      #pragma unroll
      for (int ni = 0; ni < 4; ni++) {
        int n = n0 + wn + ni*16 + col;
        float bias = b0[n];
        #pragma unroll
        for (int r = 0; r < 4; r++) {
          int m = m0 + wm + mi*16 + quad*4 + r;   // C/D: row = quad*4+reg, col = lane&15
          Cf[(size_t)m*N + n] = acc[mi][ni][r] + bias;
        }
      }
  } else {
    const int seg = n0 >> 10;   // 0=Q, 1=K, 2=V
    const float* bias = (seg == 0) ? b0 : (seg == 1) ? b1 : b2;
    const float scl = (seg == 0) ? CEXP : 1.0f;
    #pragma unroll
    for (int mi = 0; mi < MF; mi++)
      #pragma unroll
      for (int ni = 0; ni < 4; ni++) {
        int n = n0 + wn + ni*16 + col;
        float bv = bias[n & (HIDDEN-1)];
        #pragma unroll
        for (int r = 0; r < 4; r++) {
          int m = m0 + wm + mi*16 + quad*4 + r;
          Cq[(size_t)m*N + n] = f2bf((acc[mi][ni][r] + bv) * scl);
        }
      }
  }
}

// ---------------- flash attention, 32x32 MFMA, fully in-register P (T12) ----------------
// block: 128 q of one (b,h); 4 waves x 32 q. Double-buffered K/V LDS, ONE barrier/iter.
// S^T = K Q^T (A=K, B=Q): C-layout col = q = lane&31, rows t = (reg&3)+8*(reg>>2)+4*(lane>>5).
// PV B-frag (n=q=lane&31, k=t=(lane>>5)*8+j) has the SAME lane->q mapping, so the only
// data movement is cvt_pk to bf16 pairs + permlane32_swap across the lane<32/>=32 halves
// (one swap yields two fragment words). No P LDS buffer, no fence, no DS round-trip.
// Q pre-scaled by CEXP -> p = exp2(s) via raw v_exp_f32. Row sums via ones-MFMA.
__global__ __launch_bounds__(256) void attn_kernel(const u16* __restrict__ qkv,
                                                   const u16* __restrict__ vt,
                                                   u16* __restrict__ ao) {
  __shared__ u16 Ks[2*64*72];    // [buf][t][d], stride 72
  __shared__ u16 Vs[2*64*72];    // [buf][d][t], stride 72
  const int tid = threadIdx.x, lane = tid & 63, wv = tid >> 6;
  const int qt = blockIdx.x, bh = blockIdx.y;
  const int b = bh >> 4, h = bh & 15;
  const int l31 = lane & 31, hl = lane >> 5;

  // Q as 32x32x16 B-frags: n=q=l31, elem j at d = kk*16 + hl*8 + j
  bf16x8 qf[4];
  {
    const u16* qrow = qkv + (size_t)(b*SEQ + qt*128 + wv*32 + l31)*(3*HIDDEN) + h*HD + hl*8;
    #pragma unroll
    for (int kk = 0; kk < 4; kk++) qf[kk] = *(const bf16x8*)(qrow + kk*16);
  }
  bf16x8 ones;
  #pragma unroll
  for (int i = 0; i < 8; i++) ones[i] = (__bf16)1.0f;

  f32x16 o[2] = {};    // O^T acc [mt]: col=q, rows d = mt*32 + (reg&3)+8*(reg>>2)+4*hl
  f32x16 rs = {};      // row-sum acc via ones-MFMA (all regs carry rs[q])

  const int r0 = tid >> 3, r1 = (tid >> 3) + 32, koS = (tid & 7) * 8;
  const u16* gK = qkv + (size_t)b*SEQ*(3*HIDDEN) + HIDDEN + (size_t)h*HD;   // row stride 3072
  const u16* gV = vt + (size_t)bh*HD*SEQ;                                    // row stride 2048
  uint4 pK0 = *(const uint4*)&gK[(size_t)r0*(3*HIDDEN) + koS];
  uint4 pK1 = *(const uint4*)&gK[(size_t)r1*(3*HIDDEN) + koS];
  uint4 pV0 = *(const uint4*)&gV[(size_t)r0*SEQ + koS];
  uint4 pV1 = *(const uint4*)&gV[(size_t)r1*SEQ + koS];

  for (int it = 0; it < SEQ/64; ++it) {
    const int cur = (it & 1) * 4608;
    *(uint4*)&Ks[cur + r0*72 + koS] = pK0;
    *(uint4*)&Ks[cur + r1*72 + koS] = pK1;
    *(uint4*)&Vs[cur + r0*72 + koS] = pV0;
    *(uint4*)&Vs[cur + r1*72 + koS] = pV1;
    __syncthreads();   // tile it visible; other waves at most read the other buffer
    if (it < SEQ/64 - 1) {   // prefetch after barrier: loads fly during compute
      int t0 = (it + 1) * 64;
      pK0 = *(const uint4*)&gK[(size_t)(t0 + r0)*(3*HIDDEN) + koS];
      pK1 = *(const uint4*)&gK[(size_t)(t0 + r1)*(3*HIDDEN) + koS];
      pV0 = *(const uint4*)&gV[(size_t)r0*SEQ + t0 + koS];
      pV1 = *(const uint4*)&gV[(size_t)r1*SEQ + t0 + koS];
    }

    // S^T = K Q^T: two 32x32 t-subtiles, 4 k-steps of 16 over d
    f32x16 s[2] = {};
    #pragma unroll
    for (int kk = 0; kk < 4; kk++) {
      #pragma unroll
      for (int tt = 0; tt < 2; tt++) {
        bf16x8 kf = *(const bf16x8*)&Ks[cur + (tt*32 + l31)*72 + kk*16 + hl*8];
        s[tt] = __builtin_amdgcn_mfma_f32_32x32x16_bf16(kf, qf[kk], s[tt], 0, 0, 0);
      }
    }

    // per t-subtile: exp2 -> packed bf16 -> permlane into PV fragments -> PV MFMAs
    // (softmax of tt=1 overlaps PV MFMAs of tt=0 on separate pipes)
    #pragma unroll
    for (int tt = 0; tt < 2; tt++) {
      unsigned w[8];
      #pragma unroll
      for (int j = 0; j < 8; j++) {
        float p0 = EXP2(s[tt][2*j]);
        float p1 = EXP2(s[tt][2*j+1]);
        w[j] = pack2bf(p0, p1);      // t-pair {8*(j>>1)+2*(j&1)+4*hl, +1}
      }
      // swap reg-halves across lane<32 / lane>=32: w holds t = {0..3,8..11,...}+4hl,
      // fragments need t = chunk + 8*hl + {0..7}
      u32x2 r02 = __builtin_amdgcn_permlane32_swap(w[0], w[2], false, false);
      u32x2 r13 = __builtin_amdgcn_permlane32_swap(w[1], w[3], false, false);
      u32x2 r46 = __builtin_amdgcn_permlane32_swap(w[4], w[6], false, false);
      u32x2 r57 = __builtin_amdgcn_permlane32_swap(w[5], w[7], false, false);
      u32x4 c0, c1;
      c0.x = r02[0]; c0.y = r13[0]; c0.z = r02[1]; c0.w = r13[1];   // t-chunk tt*32 + 0..15
      c1.x = r46[0]; c1.y = r57[0]; c1.z = r46[1]; c1.w = r57[1];   // t-chunk tt*32 + 16..31
      bf16x8 pf0 = __builtin_bit_cast(bf16x8, c0);
      bf16x8 pf1 = __builtin_bit_cast(bf16x8, c1);

      #pragma unroll
      for (int mt = 0; mt < 2; mt++) {
        bf16x8 vf0 = *(const bf16x8*)&Vs[cur + (mt*32 + l31)*72 + tt*32 + hl*8];
        bf16x8 vf1 = *(const bf16x8*)&Vs[cur + (mt*32 + l31)*72 + tt*32 + 16 + hl*8];
        o[mt] = __builtin_amdgcn_mfma_f32_32x32x16_bf16(vf0, pf0, o[mt], 0, 0, 0);
        o[mt] = __builtin_amdgcn_mfma_f32_32x32x16_bf16(vf1, pf1, o[mt], 0, 0, 0);
      }
      rs = __builtin_amdgcn_mfma_f32_32x32x16_bf16(ones, pf0, rs, 0, 0, 0);
      rs = __builtin_amdgcn_mfma_f32_32x32x16_bf16(ones, pf1, rs, 0, 0, 0);
    }
  }

  // normalize and store O^T -> ao[q][h*64+d]; lane's column q = l31 fixed
  float inv = 1.0f / rs[0];
  u16* aop = ao + (size_t)(b*SEQ + qt*128 + wv*32 + l31)*HIDDEN + h*HD + hl*4;
  #pragma unroll
  for (int mt = 0; mt < 2; mt++)
    #pragma unroll
    for (int a4 = 0; a4 < 4; a4++) {
      uint2 w2;
      w2.x = pack2bf(o[mt][4*a4+0]*inv, o[mt][4*a4+1]*inv);
      w2.y = pack2bf(o[mt][4*a4+2]*inv, o[mt][4*a4+3]*inv);
      *(uint2*)&aop[mt*32 + 8*a4] = w2;
    }
}

extern "C" void kernel_launch(void* const* d_in, const int* in_sizes, int n_in,
                              void* d_out, int out_size, void* d_ws, size_t ws_size,
                              hipStream_t stream) {
  const float* x  = (const float*)d_in[0];
  const float* Wq = (const float*)d_in[1];
  const float* bq = (const float*)d_in[2];
  const float* Wk = (const float*)d_in[3];
  const float* bk = (const float*)d_in[4];
  const float* Wv = (const float*)d_in[5];
  const float* bv = (const float*)d_in[6];
  const float* Wo = (const float*)d_in[7];
  const float* bo = (const float*)d_in[8];
  float* out = (float*)d_out;

  char* w = (char*)d_ws;
  u16* xb    = (u16*)w; w += (size_t)MTOT*HIDDEN*2;        // 8 MB
  u16* wtqkv = (u16*)w; w += (size_t)3*HIDDEN*HIDDEN*2;    // 6 MB
  u16* wto   = (u16*)w; w += (size_t)HIDDEN*HIDDEN*2;      // 2 MB
  u16* qkvb  = (u16*)w; w += (size_t)MTOT*3*HIDDEN*2;      // 24 MB
  u16* vtb   = (u16*)w; w += (size_t)BATCH*NH*HD*SEQ*2;    // 8 MB
  u16* aob   = (u16*)w; w += (size_t)MTOT*HIDDEN*2;        // 8 MB

  convert_x_kernel<<<(MTOT*HIDDEN)/1024, 256, 0, stream>>>(x, xb);
  transpose_w_kernel<<<dim3(32, 32, 4), 256, 0, stream>>>(Wq, Wk, Wv, Wo, wtqkv, wto);
  gemm_bt<1,128><<<dim3(32, 24), 256, 0, stream>>>(xb, wtqkv, bq, bk, bv, qkvb, nullptr, MTOT, 3*HIDDEN, HIDDEN);
  transpose_v_kernel<<<dim3(SEQ/32, 2, BATCH*NH), 256, 0, stream>>>(qkvb, vtb);
  attn_kernel<<<dim3(SEQ/128, BATCH*NH), 256, 0, stream>>>(qkvb, vtb, aob);
  gemm_bt<0,64><<<dim3(64, 8), 256, 0, stream>>>(aob, wto, bo, nullptr, nullptr, nullptr, out, MTOT, HIDDEN, HIDDEN);
}